// Round 17
// baseline (78.261 us; speedup 1.0000x reference)
//
#include <hip/hip_runtime.h>
#include <hip/hip_bf16.h>

// DualMem fast_get_image_pred:
//   logits[b,c] = 100 * (Σ_m w_m sim_m) / sqrt(Σ_{i,j} w_i w_j G[c,i,j])
//
// Lesson ledger (17 rounds):
//  - Spill triggers: (a) launch_bounds 2nd arg / non-256 blocks / >=48KB LDS
//    starve the allocator; (b) local arrays passed to helpers -> scratch.
//  - R12-R16: per-wave ILP tricks (pragma unroll, WAR rotation, independent
//    chains) CANNOT shorten a serial load->mfma K-chain: compiler sinks
//    loads to uses; 56us flat across all four structures. Occupancy ~27%
//    (2 blocks/CU co-resident) means chains barely overlap.
//    => attack the chain LENGTH and wave COUNT directly: SPLIT-K.
//  - Split-K partitions mem reads exactly (no cross-XCD duplication).
//  - R4: lane-duplicated addresses are wave-duplicated through L1.
//  - MFMA C-layout col=lane&15, row=(lane>>4)*4+reg (verified R12/R13).
//
// Structure (S = 4 K-splits, ws-guarded):
//   K1 sim:  grid(1000,S); wave w: 16b x 16m tile, K-range kq*256..+256 as
//            4 rounds x 2 chains. Partials to ws_sim[S][1000][64][11].
//   K2 gram: grid(250,S); wave w: class 4*bx+w, same K-split, A==B MFMA.
//            Partials to ws_gram[S][1000][121].
//   K3 finish: grid(250); sums S slices inline (L1-broadcast reads).

constexpr int Bn = 64;     // batch
constexpr int Cn = 1000;   // classes
constexpr int Mn = 11;     // memories per class
constexpr int Dn = 1024;   // feature dim
constexpr float BETA = 5.5f;

typedef __attribute__((ext_vector_type(8))) short bf16x8;
typedef __attribute__((ext_vector_type(4))) float f32x4;

__device__ inline short f2bf(float x) {
    union { __hip_bfloat16 h; short s; } u;
    u.h = __float2bfloat16(x);
    return u.s;
}

__device__ inline bf16x8 pack_bf16x8(const float4 a, const float4 b) {
    bf16x8 r;
    r[0] = f2bf(a.x); r[1] = f2bf(a.y); r[2] = f2bf(a.z); r[3] = f2bf(a.w);
    r[4] = f2bf(b.x); r[5] = f2bf(b.y); r[6] = f2bf(b.z); r[7] = f2bf(b.w);
    return r;
}

// ---------------- K1: sim partials via MFMA, split-K ----------------
template <int S>
__global__ __launch_bounds__(256) void sim_kernel(
    const float* __restrict__ img, const float* __restrict__ mem,
    float* __restrict__ simp) {
    const int c  = blockIdx.x;
    const int kq = blockIdx.y;         // K-split index
    const int w  = threadIdx.x >> 6;   // wave: b-tile (16 rows)
    const int l  = threadIdx.x & 63;
    const int rw = l & 15;             // A-row (b_local) / B-row (m)
    const int kb = (l >> 4) * 8;       // per-lane k-offset within a K=32 step
    constexpr int STEPS = 32 / S;      // K-steps of 32 in this split

    const float* ipA = img + (w * 16 + rw) * Dn + kq * (Dn / S) + kb;
    const int mrow = (rw < Mn) ? rw : 0;   // pad rows alias row 0
    const float* ipB = mem + (size_t)c * (Mn * Dn) + mrow * Dn + kq * (Dn / S) + kb;

    // 2 independent chains; chain j covers steps {2r+j}
    f32x4 acc0 = {0.f, 0.f, 0.f, 0.f};
    f32x4 acc1 = {0.f, 0.f, 0.f, 0.f};
#pragma unroll
    for (int r = 0; r < STEPS / 2; ++r) {
        const int k0 = 64 * r;
        const float4 a00 = *reinterpret_cast<const float4*>(ipA + k0);
        const float4 a01 = *reinterpret_cast<const float4*>(ipA + k0 + 4);
        const float4 b00 = *reinterpret_cast<const float4*>(ipB + k0);
        const float4 b01 = *reinterpret_cast<const float4*>(ipB + k0 + 4);
        const float4 a10 = *reinterpret_cast<const float4*>(ipA + k0 + 32);
        const float4 a11 = *reinterpret_cast<const float4*>(ipA + k0 + 36);
        const float4 b10 = *reinterpret_cast<const float4*>(ipB + k0 + 32);
        const float4 b11 = *reinterpret_cast<const float4*>(ipB + k0 + 36);
        acc0 = __builtin_amdgcn_mfma_f32_16x16x32_bf16(
            pack_bf16x8(a00, a01), pack_bf16x8(b00, b01), acc0, 0, 0, 0);
        acc1 = __builtin_amdgcn_mfma_f32_16x16x32_bf16(
            pack_bf16x8(a10, a11), pack_bf16x8(b10, b11), acc1, 0, 0, 0);
    }
    const f32x4 acc = acc0 + acc1;

    // C layout: col = l&15 (m), row = (l>>4)*4 + reg (b_local)
    const int mcol = l & 15;
    if (mcol < Mn) {
        const int br = w * 16 + (l >> 4) * 4;
        float* o = simp + ((size_t)kq * Cn + c) * (Bn * Mn) + br * Mn + mcol;
        o[0 * Mn] = acc[0];
        o[1 * Mn] = acc[1];
        o[2 * Mn] = acc[2];
        o[3 * Mn] = acc[3];
    }
}

// ---------------- K2: gram partials via MFMA (A==B), split-K ----------------
template <int S>
__global__ __launch_bounds__(256) void gram_kernel(
    const float* __restrict__ mem, float* __restrict__ gramp) {
    const int c  = blockIdx.x * 4 + (threadIdx.x >> 6);  // wave -> class
    const int kq = blockIdx.y;
    const int l  = threadIdx.x & 63;
    const int rw = l & 15;
    const int kb = (l >> 4) * 8;
    constexpr int STEPS = 32 / S;

    const int mrow = (rw < Mn) ? rw : 0;   // pad rows alias row 0
    const float* ip = mem + (size_t)c * (Mn * Dn) + mrow * Dn + kq * (Dn / S) + kb;

    f32x4 acc0 = {0.f, 0.f, 0.f, 0.f};
    f32x4 acc1 = {0.f, 0.f, 0.f, 0.f};
#pragma unroll
    for (int r = 0; r < STEPS / 2; ++r) {
        const int k0 = 64 * r;
        const float4 a00 = *reinterpret_cast<const float4*>(ip + k0);
        const float4 a01 = *reinterpret_cast<const float4*>(ip + k0 + 4);
        const float4 a10 = *reinterpret_cast<const float4*>(ip + k0 + 32);
        const float4 a11 = *reinterpret_cast<const float4*>(ip + k0 + 36);
        const bf16x8 f0 = pack_bf16x8(a00, a01);
        const bf16x8 f1 = pack_bf16x8(a10, a11);
        acc0 = __builtin_amdgcn_mfma_f32_16x16x32_bf16(f0, f0, acc0, 0, 0, 0);
        acc1 = __builtin_amdgcn_mfma_f32_16x16x32_bf16(f1, f1, acc1, 0, 0, 0);
    }
    const f32x4 acc = acc0 + acc1;

    // C[i][j] = mem_i . mem_j over this K-range (symmetric)
    const int col = l & 15;
    const int r0  = (l >> 4) * 4;
    if (col < Mn) {
        float* o = gramp + ((size_t)kq * Cn + c) * (Mn * Mn) + col;
        if (r0 + 0 < Mn) o[(r0 + 0) * Mn] = acc[0];
        if (r0 + 1 < Mn) o[(r0 + 1) * Mn] = acc[1];
        if (r0 + 2 < Mn) o[(r0 + 2) * Mn] = acc[2];
        if (r0 + 3 < Mn) o[(r0 + 3) * Mn] = acc[3];
    }
}

// ---------------- K3: logits (sums S partial slices) ----------------
template <int S>
__global__ __launch_bounds__(256) void finish_kernel(
    const float* __restrict__ simp, const float* __restrict__ gramp,
    float* __restrict__ out) {
    const int b = threadIdx.x & 63;
    const int c = blockIdx.x * 4 + (threadIdx.x >> 6);

    const float* sp = simp + (size_t)c * (Bn * Mn) + b * Mn;
    const float* gp = gramp + (size_t)c * (Mn * Mn);
    constexpr size_t SIMSTR  = (size_t)Cn * Bn * Mn;
    constexpr size_t GRAMSTR = (size_t)Cn * Mn * Mn;

    float w[Mn];
    float numer = 0.f;
#pragma unroll
    for (int m = 0; m < Mn; ++m) {
        float s = 0.f;
#pragma unroll
        for (int q = 0; q < S; ++q) s += sp[q * SIMSTR + m];
        w[m]  = __expf(BETA * (s - 1.f));
        numer = fmaf(w[m], s, numer);
    }
    float den2 = 0.f;
#pragma unroll
    for (int i = 0; i < Mn; ++i) {
        float row = 0.f;
#pragma unroll
        for (int j = 0; j < Mn; ++j) {
            float Gv = 0.f;
#pragma unroll
            for (int q = 0; q < S; ++q) Gv += gp[q * GRAMSTR + i * Mn + j];
            row = fmaf(w[j], Gv, row);
        }
        den2 = fmaf(w[i], row, den2);
    }
    out[b * Cn + c] = 100.f * numer / sqrtf(den2);
}

extern "C" void kernel_launch(void* const* d_in, const int* in_sizes, int n_in,
                              void* d_out, int out_size, void* d_ws, size_t ws_size,
                              hipStream_t stream) {
    const float* img = (const float*)d_in[0];  // [64][1024] f32
    const float* mem = (const float*)d_in[1];  // [1000][11][1024] f32
    float* out = (float*)d_out;                // [64][1000] f32
    (void)in_sizes; (void)n_in; (void)out_size;

    const size_t need4 = ((size_t)4 * Cn * Bn * Mn + (size_t)4 * Cn * Mn * Mn)
                         * sizeof(float);
    if (ws_size >= need4) {
        constexpr int S = 4;
        float* ws_sim  = (float*)d_ws;                       // [S][1000][64][11]
        float* ws_gram = ws_sim + (size_t)S * Cn * Bn * Mn;  // [S][1000][11][11]
        sim_kernel<S><<<dim3(Cn, S), dim3(256), 0, stream>>>(img, mem, ws_sim);
        gram_kernel<S><<<dim3(Cn / 4, S), dim3(256), 0, stream>>>(mem, ws_gram);
        finish_kernel<S><<<dim3(Cn / 4), dim3(256), 0, stream>>>(ws_sim, ws_gram, out);
    } else {
        constexpr int S = 1;
        float* ws_sim  = (float*)d_ws;
        float* ws_gram = ws_sim + (size_t)S * Cn * Bn * Mn;
        sim_kernel<S><<<dim3(Cn, S), dim3(256), 0, stream>>>(img, mem, ws_sim);
        gram_kernel<S><<<dim3(Cn / 4, S), dim3(256), 0, stream>>>(mem, ws_gram);
        finish_kernel<S><<<dim3(Cn / 4), dim3(256), 0, stream>>>(ws_sim, ws_gram, out);
    }
}

// Round 18
// 51.501 us; speedup vs baseline: 1.5196x; 1.5196x over previous
//
#include <hip/hip_runtime.h>
#include <hip/hip_bf16.h>

// DualMem fast_get_image_pred:
//   logits[b,c] = 100 * (Σ_m w_m sim_m) / sqrt(Σ_{i,j} w_i w_j G[c,i,j])
//
// Lesson ledger (18 rounds):
//  - Spill triggers: launch_bounds 2nd arg / non-256 blocks / >=48KB LDS
//    starve the allocator; local arrays passed to helpers go to scratch.
//  - R12-R17: MFMA sim flat at ~57us across serial/rotation/chains/split-K,
//    occupancy 27->63% with NO time change. Diagnosis: fragment loads make
//    lane l read row l&15 -> each wave-wide load touches 16 cache lines
//    4KB apart; L1/TA processes ~1 line/cyc -> 15.6 blk/CU x 4 waves x 128
//    loads x 16 lines = 128K cyc = 53us. Address-path throughput, invisible
//    in MfmaUtil/VALUBusy/HBM counters, independent of occupancy and ILP.
//    FIX: pre-pack operands into fragment-ordered bf16 so every hot load is
//    64 lanes x 16B CONTIGUOUS (8 lines), and loads halve (bf16 vs f32).
//  - R4: lane-duplicated addresses are wave-duplicated through L1.
//  - MFMA C-layout col=lane&15, row=(lane>>4)*4+reg (verified R12/R13).
//
// Structure:
//   P1 pack_img: imgP[4][32][64] bf16x8 fragments (128 KB).
//   P2 pack_mem: memP[1000][32][64] bf16x8 fragments (32.8 MB).
//   K1 sim<S>:  grid(1000,S); contiguous fragment loads; partials to ws.
//   K2 gram<S>: grid(250,S); A==B from memP.
//   K3 finish<S>: sums S slices, logits.
//   ws-guarded fallback to unpacked variants if ws is small.

constexpr int Bn = 64;     // batch
constexpr int Cn = 1000;   // classes
constexpr int Mn = 11;     // memories per class
constexpr int Dn = 1024;   // feature dim
constexpr float BETA = 5.5f;

typedef __attribute__((ext_vector_type(8))) short bf16x8;
typedef __attribute__((ext_vector_type(4))) float f32x4;

__device__ inline short f2bf(float x) {
    union { __hip_bfloat16 h; short s; } u;
    u.h = __float2bfloat16(x);
    return u.s;
}

__device__ inline bf16x8 pack_bf16x8(const float4 a, const float4 b) {
    bf16x8 r;
    r[0] = f2bf(a.x); r[1] = f2bf(a.y); r[2] = f2bf(a.z); r[3] = f2bf(a.w);
    r[4] = f2bf(b.x); r[5] = f2bf(b.y); r[6] = f2bf(b.z); r[7] = f2bf(b.w);
    return r;
}

// ---------------- P1: imgP fragments ----------------
// chunk t: w=t>>11, kstep=(t>>6)&31, l=t&63 -> img[w*16+(l&15)][kstep*32+(l>>4)*8 ..+7]
__global__ __launch_bounds__(256) void pack_img_kernel(
    const float* __restrict__ img, bf16x8* __restrict__ imgP) {
    const int t = blockIdx.x * 256 + threadIdx.x;   // 8192 chunks
    const int l = t & 63;
    const int kstep = (t >> 6) & 31;
    const int w = t >> 11;
    const int row = w * 16 + (l & 15);
    const int kcol = kstep * 32 + (l >> 4) * 8;
    const float4 a0 = *reinterpret_cast<const float4*>(img + row * Dn + kcol);
    const float4 a1 = *reinterpret_cast<const float4*>(img + row * Dn + kcol + 4);
    imgP[t] = pack_bf16x8(a0, a1);
}

// ---------------- P2: memP fragments ----------------
__global__ __launch_bounds__(256) void pack_mem_kernel(
    const float* __restrict__ mem, bf16x8* __restrict__ memP) {
    const int c = blockIdx.x;
#pragma unroll
    for (int j = 0; j < 8; ++j) {
        const int chunk = threadIdx.x + j * 256;    // 2048 chunks/class
        const int l = chunk & 63;
        const int kstep = chunk >> 6;
        const int rw = l & 15;
        const int mrow = (rw < Mn) ? rw : 0;        // pad rows alias row 0
        const int kcol = kstep * 32 + (l >> 4) * 8;
        const float* p = mem + (size_t)c * (Mn * Dn) + mrow * Dn + kcol;
        const float4 a0 = *reinterpret_cast<const float4*>(p);
        const float4 a1 = *reinterpret_cast<const float4*>(p + 4);
        memP[(size_t)c * 2048 + chunk] = pack_bf16x8(a0, a1);
    }
}

// ---------------- K1: sim partials, packed loads ----------------
template <int S>
__global__ __launch_bounds__(256) void sim_kernel(
    const bf16x8* __restrict__ imgP, const bf16x8* __restrict__ memP,
    float* __restrict__ simp) {
    const int c  = blockIdx.x;
    const int kq = blockIdx.y;
    const int w  = threadIdx.x >> 6;   // wave: b-tile
    const int l  = threadIdx.x & 63;
    constexpr int STEPS = 32 / S;

    const bf16x8* pA = imgP + (w * 32 + kq * STEPS) * 64 + l;
    const bf16x8* pB = memP + ((size_t)c * 32 + kq * STEPS) * 64 + l;

    // 2 independent chains
    f32x4 acc0 = {0.f, 0.f, 0.f, 0.f};
    f32x4 acc1 = {0.f, 0.f, 0.f, 0.f};
#pragma unroll
    for (int r = 0; r < STEPS / 2; ++r) {
        const bf16x8 a0 = pA[(2 * r) * 64];
        const bf16x8 b0 = pB[(2 * r) * 64];
        const bf16x8 a1 = pA[(2 * r + 1) * 64];
        const bf16x8 b1 = pB[(2 * r + 1) * 64];
        acc0 = __builtin_amdgcn_mfma_f32_16x16x32_bf16(a0, b0, acc0, 0, 0, 0);
        acc1 = __builtin_amdgcn_mfma_f32_16x16x32_bf16(a1, b1, acc1, 0, 0, 0);
    }
    const f32x4 acc = acc0 + acc1;

    // C layout: col = l&15 (m), row = (l>>4)*4 + reg (b_local)
    const int mcol = l & 15;
    if (mcol < Mn) {
        const int br = w * 16 + (l >> 4) * 4;
        float* o = simp + ((size_t)kq * Cn + c) * (Bn * Mn) + br * Mn + mcol;
        o[0 * Mn] = acc[0];
        o[1 * Mn] = acc[1];
        o[2 * Mn] = acc[2];
        o[3 * Mn] = acc[3];
    }
}

// ---------------- K2: gram partials, packed loads (A==B) ----------------
template <int S>
__global__ __launch_bounds__(256) void gram_kernel(
    const bf16x8* __restrict__ memP, float* __restrict__ gramp) {
    const int c  = blockIdx.x * 4 + (threadIdx.x >> 6);
    const int kq = blockIdx.y;
    const int l  = threadIdx.x & 63;
    constexpr int STEPS = 32 / S;

    const bf16x8* pB = memP + ((size_t)c * 32 + kq * STEPS) * 64 + l;

    f32x4 acc0 = {0.f, 0.f, 0.f, 0.f};
    f32x4 acc1 = {0.f, 0.f, 0.f, 0.f};
#pragma unroll
    for (int r = 0; r < STEPS / 2; ++r) {
        const bf16x8 f0 = pB[(2 * r) * 64];
        const bf16x8 f1 = pB[(2 * r + 1) * 64];
        acc0 = __builtin_amdgcn_mfma_f32_16x16x32_bf16(f0, f0, acc0, 0, 0, 0);
        acc1 = __builtin_amdgcn_mfma_f32_16x16x32_bf16(f1, f1, acc1, 0, 0, 0);
    }
    const f32x4 acc = acc0 + acc1;

    const int col = l & 15;
    const int r0  = (l >> 4) * 4;
    if (col < Mn) {
        float* o = gramp + ((size_t)kq * Cn + c) * (Mn * Mn) + col;
        if (r0 + 0 < Mn) o[(r0 + 0) * Mn] = acc[0];
        if (r0 + 1 < Mn) o[(r0 + 1) * Mn] = acc[1];
        if (r0 + 2 < Mn) o[(r0 + 2) * Mn] = acc[2];
        if (r0 + 3 < Mn) o[(r0 + 3) * Mn] = acc[3];
    }
}

// ---------------- unpacked fallbacks (R17-proven) ----------------
template <int S>
__global__ __launch_bounds__(256) void sim_kernel_u(
    const float* __restrict__ img, const float* __restrict__ mem,
    float* __restrict__ simp) {
    const int c  = blockIdx.x;
    const int kq = blockIdx.y;
    const int w  = threadIdx.x >> 6;
    const int l  = threadIdx.x & 63;
    const int rw = l & 15;
    const int kb = (l >> 4) * 8;
    constexpr int STEPS = 32 / S;

    const float* ipA = img + (w * 16 + rw) * Dn + kq * (Dn / S) + kb;
    const int mrow = (rw < Mn) ? rw : 0;
    const float* ipB = mem + (size_t)c * (Mn * Dn) + mrow * Dn + kq * (Dn / S) + kb;

    f32x4 acc0 = {0.f, 0.f, 0.f, 0.f};
    f32x4 acc1 = {0.f, 0.f, 0.f, 0.f};
#pragma unroll
    for (int r = 0; r < STEPS / 2; ++r) {
        const int k0 = 64 * r;
        const float4 a00 = *reinterpret_cast<const float4*>(ipA + k0);
        const float4 a01 = *reinterpret_cast<const float4*>(ipA + k0 + 4);
        const float4 b00 = *reinterpret_cast<const float4*>(ipB + k0);
        const float4 b01 = *reinterpret_cast<const float4*>(ipB + k0 + 4);
        const float4 a10 = *reinterpret_cast<const float4*>(ipA + k0 + 32);
        const float4 a11 = *reinterpret_cast<const float4*>(ipA + k0 + 36);
        const float4 b10 = *reinterpret_cast<const float4*>(ipB + k0 + 32);
        const float4 b11 = *reinterpret_cast<const float4*>(ipB + k0 + 36);
        acc0 = __builtin_amdgcn_mfma_f32_16x16x32_bf16(
            pack_bf16x8(a00, a01), pack_bf16x8(b00, b01), acc0, 0, 0, 0);
        acc1 = __builtin_amdgcn_mfma_f32_16x16x32_bf16(
            pack_bf16x8(a10, a11), pack_bf16x8(b10, b11), acc1, 0, 0, 0);
    }
    const f32x4 acc = acc0 + acc1;

    const int mcol = l & 15;
    if (mcol < Mn) {
        const int br = w * 16 + (l >> 4) * 4;
        float* o = simp + ((size_t)kq * Cn + c) * (Bn * Mn) + br * Mn + mcol;
        o[0 * Mn] = acc[0];
        o[1 * Mn] = acc[1];
        o[2 * Mn] = acc[2];
        o[3 * Mn] = acc[3];
    }
}

template <int S>
__global__ __launch_bounds__(256) void gram_kernel_u(
    const float* __restrict__ mem, float* __restrict__ gramp) {
    const int c  = blockIdx.x * 4 + (threadIdx.x >> 6);
    const int kq = blockIdx.y;
    const int l  = threadIdx.x & 63;
    const int rw = l & 15;
    const int kb = (l >> 4) * 8;
    constexpr int STEPS = 32 / S;

    const int mrow = (rw < Mn) ? rw : 0;
    const float* ip = mem + (size_t)c * (Mn * Dn) + mrow * Dn + kq * (Dn / S) + kb;

    f32x4 acc0 = {0.f, 0.f, 0.f, 0.f};
    f32x4 acc1 = {0.f, 0.f, 0.f, 0.f};
#pragma unroll
    for (int r = 0; r < STEPS / 2; ++r) {
        const int k0 = 64 * r;
        const float4 a00 = *reinterpret_cast<const float4*>(ip + k0);
        const float4 a01 = *reinterpret_cast<const float4*>(ip + k0 + 4);
        const float4 a10 = *reinterpret_cast<const float4*>(ip + k0 + 32);
        const float4 a11 = *reinterpret_cast<const float4*>(ip + k0 + 36);
        const bf16x8 f0 = pack_bf16x8(a00, a01);
        const bf16x8 f1 = pack_bf16x8(a10, a11);
        acc0 = __builtin_amdgcn_mfma_f32_16x16x32_bf16(f0, f0, acc0, 0, 0, 0);
        acc1 = __builtin_amdgcn_mfma_f32_16x16x32_bf16(f1, f1, acc1, 0, 0, 0);
    }
    const f32x4 acc = acc0 + acc1;

    const int col = l & 15;
    const int r0  = (l >> 4) * 4;
    if (col < Mn) {
        float* o = gramp + ((size_t)kq * Cn + c) * (Mn * Mn) + col;
        if (r0 + 0 < Mn) o[(r0 + 0) * Mn] = acc[0];
        if (r0 + 1 < Mn) o[(r0 + 1) * Mn] = acc[1];
        if (r0 + 2 < Mn) o[(r0 + 2) * Mn] = acc[2];
        if (r0 + 3 < Mn) o[(r0 + 3) * Mn] = acc[3];
    }
}

// ---------------- K3: logits (sums S partial slices) ----------------
template <int S>
__global__ __launch_bounds__(256) void finish_kernel(
    const float* __restrict__ simp, const float* __restrict__ gramp,
    float* __restrict__ out) {
    const int b = threadIdx.x & 63;
    const int c = blockIdx.x * 4 + (threadIdx.x >> 6);

    const float* sp = simp + (size_t)c * (Bn * Mn) + b * Mn;
    const float* gp = gramp + (size_t)c * (Mn * Mn);
    constexpr size_t SIMSTR  = (size_t)Cn * Bn * Mn;
    constexpr size_t GRAMSTR = (size_t)Cn * Mn * Mn;

    float w[Mn];
    float numer = 0.f;
#pragma unroll
    for (int m = 0; m < Mn; ++m) {
        float s = 0.f;
#pragma unroll
        for (int q = 0; q < S; ++q) s += sp[q * SIMSTR + m];
        w[m]  = __expf(BETA * (s - 1.f));
        numer = fmaf(w[m], s, numer);
    }
    float den2 = 0.f;
#pragma unroll
    for (int i = 0; i < Mn; ++i) {
        float row = 0.f;
#pragma unroll
        for (int j = 0; j < Mn; ++j) {
            float Gv = 0.f;
#pragma unroll
            for (int q = 0; q < S; ++q) Gv += gp[q * GRAMSTR + i * Mn + j];
            row = fmaf(w[j], Gv, row);
        }
        den2 = fmaf(w[i], row, den2);
    }
    out[b * Cn + c] = 100.f * numer / sqrtf(den2);
}

extern "C" void kernel_launch(void* const* d_in, const int* in_sizes, int n_in,
                              void* d_out, int out_size, void* d_ws, size_t ws_size,
                              hipStream_t stream) {
    const float* img = (const float*)d_in[0];  // [64][1024] f32
    const float* mem = (const float*)d_in[1];  // [1000][11][1024] f32
    float* out = (float*)d_out;                // [64][1000] f32
    (void)in_sizes; (void)n_in; (void)out_size;

    constexpr size_t IMGP_B  = (size_t)4 * 32 * 64 * 16;        // 131072
    constexpr size_t MEMP_B  = (size_t)Cn * 32 * 64 * 16;       // 32768000
    constexpr size_t SIMP_B  = (size_t)Cn * Bn * Mn * 4;        // per slice
    constexpr size_t GRAMP_B = (size_t)Cn * Mn * Mn * 4;        // per slice

    char* base = (char*)d_ws;
    const size_t need_p4 = IMGP_B + MEMP_B + 4 * SIMP_B + 4 * GRAMP_B;  // ~46.1MB
    const size_t need_p1 = IMGP_B + MEMP_B + SIMP_B + GRAMP_B;          // ~36.2MB
    const size_t need_u4 = 4 * SIMP_B + 4 * GRAMP_B;                    // ~13.2MB

    if (ws_size >= need_p4 || ws_size >= need_p1) {
        bf16x8* imgP = (bf16x8*)base;
        bf16x8* memP = (bf16x8*)(base + IMGP_B);
        float* simp  = (float*)(base + IMGP_B + MEMP_B);
        pack_img_kernel<<<dim3(32), dim3(256), 0, stream>>>(img, imgP);
        pack_mem_kernel<<<dim3(Cn), dim3(256), 0, stream>>>(mem, memP);
        if (ws_size >= need_p4) {
            constexpr int S = 4;
            float* gramp = simp + (size_t)S * Cn * Bn * Mn;
            sim_kernel<S><<<dim3(Cn, S), dim3(256), 0, stream>>>(imgP, memP, simp);
            gram_kernel<S><<<dim3(Cn / 4, S), dim3(256), 0, stream>>>(memP, gramp);
            finish_kernel<S><<<dim3(Cn / 4), dim3(256), 0, stream>>>(simp, gramp, out);
        } else {
            constexpr int S = 1;
            float* gramp = simp + (size_t)S * Cn * Bn * Mn;
            sim_kernel<S><<<dim3(Cn, S), dim3(256), 0, stream>>>(imgP, memP, simp);
            gram_kernel<S><<<dim3(Cn / 4, S), dim3(256), 0, stream>>>(memP, gramp);
            finish_kernel<S><<<dim3(Cn / 4), dim3(256), 0, stream>>>(simp, gramp, out);
        }
    } else if (ws_size >= need_u4) {
        constexpr int S = 4;
        float* simp  = (float*)base;
        float* gramp = simp + (size_t)S * Cn * Bn * Mn;
        sim_kernel_u<S><<<dim3(Cn, S), dim3(256), 0, stream>>>(img, mem, simp);
        gram_kernel_u<S><<<dim3(Cn / 4, S), dim3(256), 0, stream>>>(mem, gramp);
        finish_kernel<S><<<dim3(Cn / 4), dim3(256), 0, stream>>>(simp, gramp, out);
    } else {
        constexpr int S = 1;
        float* simp  = (float*)base;
        float* gramp = simp + (size_t)S * Cn * Bn * Mn;
        sim_kernel_u<S><<<dim3(Cn, S), dim3(256), 0, stream>>>(img, mem, simp);
        gram_kernel_u<S><<<dim3(Cn / 4, S), dim3(256), 0, stream>>>(mem, gramp);
        finish_kernel<S><<<dim3(Cn / 4), dim3(256), 0, stream>>>(simp, gramp, out);
    }
}

// Round 19
// 36.161 us; speedup vs baseline: 2.1643x; 1.4242x over previous
//
#include <hip/hip_runtime.h>
#include <hip/hip_bf16.h>

// DualMem fast_get_image_pred:
//   logits[b,c] = 100 * (Σ_m w_m sim_m) / sqrt(Σ_{i,j} w_i w_j G[c,i,j])
//
// Lesson ledger (19 rounds):
//  - Spill triggers: launch_bounds 2nd arg / non-256 blocks / >=48KB LDS
//    starve the allocator; local arrays passed to helpers go to scratch.
//  - R12-R18: MFMA fragment loads from row-major f32 touch 16 lines 4KB
//    apart per wave-load -> address-path bound at ~57us, invariant under
//    ILP/occupancy/split-K. FIX (verified R18, 78->51.5us): pre-pack both
//    operands into fragment-ordered bf16 so every hot load is 64x16B
//    contiguous. Packing cost is one linear pass.
//  - R18 counters: our kernels now < 40us each; remaining cost = redundant
//    passes + 5-deep dispatch chain. => fuse gram into pack (fragments
//    already in registers), fuse finish into sim at S=1 (S only changed
//    occupancy, never time — line count is S-invariant).
//  - MFMA C-layout col=lane&15, row=(lane>>4)*4+reg (verified R12/R13).
//
// Structure (3 dispatches):
//   P1 pack_img: imgP[4][32][64] bf16x8 fragments (128 KB).
//   P2 packgram: pack memP[1000][32][64] AND gram2[1000][11][11] (A==B MFMA
//      on just-packed register fragments; 4KB LDS cross-wave reduce).
//   K1 simfin: grid(1000); 4 waves x 32 MFMA; C-tiles -> 3KB LDS -> logits.
//   ws-guarded fallbacks (unpacked split-K, R17-proven) if ws is small.

constexpr int Bn = 64;     // batch
constexpr int Cn = 1000;   // classes
constexpr int Mn = 11;     // memories per class
constexpr int Dn = 1024;   // feature dim
constexpr float BETA = 5.5f;

typedef __attribute__((ext_vector_type(8))) short bf16x8;
typedef __attribute__((ext_vector_type(4))) float f32x4;

__device__ inline short f2bf(float x) {
    union { __hip_bfloat16 h; short s; } u;
    u.h = __float2bfloat16(x);
    return u.s;
}

__device__ inline bf16x8 pack_bf16x8(const float4 a, const float4 b) {
    bf16x8 r;
    r[0] = f2bf(a.x); r[1] = f2bf(a.y); r[2] = f2bf(a.z); r[3] = f2bf(a.w);
    r[4] = f2bf(b.x); r[5] = f2bf(b.y); r[6] = f2bf(b.z); r[7] = f2bf(b.w);
    return r;
}

// ---------------- P1: imgP fragments ----------------
__global__ __launch_bounds__(256) void pack_img_kernel(
    const float* __restrict__ img, bf16x8* __restrict__ imgP) {
    const int t = blockIdx.x * 256 + threadIdx.x;   // 8192 chunks
    const int l = t & 63;
    const int kstep = (t >> 6) & 31;
    const int w = t >> 11;
    const int row = w * 16 + (l & 15);
    const int kcol = kstep * 32 + (l >> 4) * 8;
    const float4 a0 = *reinterpret_cast<const float4*>(img + row * Dn + kcol);
    const float4 a1 = *reinterpret_cast<const float4*>(img + row * Dn + kcol + 4);
    imgP[t] = pack_bf16x8(a0, a1);
}

// ---------------- P2: pack memP + gram2 (fused, fragments in regs) ----------------
__global__ __launch_bounds__(256) void packgram_kernel(
    const float* __restrict__ mem, bf16x8* __restrict__ memP,
    float* __restrict__ gram2) {
    const int c   = blockIdx.x;
    const int tid = threadIdx.x;
    const int l   = tid & 63;
    const int w   = tid >> 6;
    const int rw  = l & 15;
    const int mrow = (rw < Mn) ? rw : 0;       // pad rows alias row 0
    const int kb   = (l >> 4) * 8;
    const float* mc = mem + (size_t)c * (Mn * Dn) + mrow * Dn + kb;

    f32x4 acc = {0.f, 0.f, 0.f, 0.f};
#pragma unroll
    for (int j = 0; j < 8; ++j) {              // wave w packs ksteps {w+4j}
        const int kstep = w + 4 * j;
        const float4 a0 = *reinterpret_cast<const float4*>(mc + kstep * 32);
        const float4 a1 = *reinterpret_cast<const float4*>(mc + kstep * 32 + 4);
        const bf16x8 f = pack_bf16x8(a0, a1);
        memP[(size_t)c * 2048 + kstep * 64 + l] = f;
        acc = __builtin_amdgcn_mfma_f32_16x16x32_bf16(f, f, acc, 0, 0, 0);
    }

    __shared__ f32x4 red[4][64];               // 4 KB
    red[w][l] = acc;
    __syncthreads();
    if (w == 0) {
        const f32x4 t = red[0][l] + red[1][l] + red[2][l] + red[3][l];
        const int col = l & 15;
        const int r0  = (l >> 4) * 4;
        if (col < Mn) {
            float* o = gram2 + (size_t)c * (Mn * Mn) + col;
            if (r0 + 0 < Mn) o[(r0 + 0) * Mn] = t[0];
            if (r0 + 1 < Mn) o[(r0 + 1) * Mn] = t[1];
            if (r0 + 2 < Mn) o[(r0 + 2) * Mn] = t[2];
            if (r0 + 3 < Mn) o[(r0 + 3) * Mn] = t[3];
        }
    }
}

// ---------------- K1: sim + finish fused ----------------
__global__ __launch_bounds__(256) void simfin_kernel(
    const bf16x8* __restrict__ imgP, const bf16x8* __restrict__ memP,
    const float* __restrict__ gram2, float* __restrict__ out) {
    const int c   = blockIdx.x;
    const int tid = threadIdx.x;
    const int l   = tid & 63;
    const int w   = tid >> 6;

    const bf16x8* pA = imgP + (size_t)w * 2048 + l;
    const bf16x8* pB = memP + (size_t)c * 2048 + l;

    // 2 independent chains over 32 K-steps
    f32x4 acc0 = {0.f, 0.f, 0.f, 0.f};
    f32x4 acc1 = {0.f, 0.f, 0.f, 0.f};
#pragma unroll
    for (int r = 0; r < 16; ++r) {
        const bf16x8 a0 = pA[(2 * r) * 64];
        const bf16x8 b0 = pB[(2 * r) * 64];
        const bf16x8 a1 = pA[(2 * r + 1) * 64];
        const bf16x8 b1 = pB[(2 * r + 1) * 64];
        acc0 = __builtin_amdgcn_mfma_f32_16x16x32_bf16(a0, b0, acc0, 0, 0, 0);
        acc1 = __builtin_amdgcn_mfma_f32_16x16x32_bf16(a1, b1, acc1, 0, 0, 0);
    }
    const f32x4 acc = acc0 + acc1;

    // C layout: col = l&15 (m), rows w*16+(l>>4)*4+{0..3} (b) -> LDS
    __shared__ float redS[Bn][12];             // 3 KB
    const int mcol = l & 15;
    const int br   = w * 16 + (l >> 4) * 4;
    if (mcol < Mn) {
        redS[br + 0][mcol] = acc[0];
        redS[br + 1][mcol] = acc[1];
        redS[br + 2][mcol] = acc[2];
        redS[br + 3][mcol] = acc[3];
    }
    __syncthreads();

    if (tid < Bn) {
        const int b = tid;
        const float* gp = gram2 + (size_t)c * (Mn * Mn);
        float wv[Mn];
        float numer = 0.f;
#pragma unroll
        for (int m = 0; m < Mn; ++m) {
            const float s = redS[b][m];
            wv[m] = __expf(BETA * (s - 1.f));
            numer = fmaf(wv[m], s, numer);
        }
        float den2 = 0.f;
#pragma unroll
        for (int i = 0; i < Mn; ++i) {
            float row = 0.f;
#pragma unroll
            for (int j = 0; j < Mn; ++j) row = fmaf(wv[j], gp[i * Mn + j], row);
            den2 = fmaf(wv[i], row, den2);
        }
        out[b * Cn + c] = 100.f * numer / sqrtf(den2);
    }
}

// ---------------- fallbacks: unpacked split-K (R17-proven) ----------------
template <int S>
__global__ __launch_bounds__(256) void sim_kernel_u(
    const float* __restrict__ img, const float* __restrict__ mem,
    float* __restrict__ simp) {
    const int c  = blockIdx.x;
    const int kq = blockIdx.y;
    const int w  = threadIdx.x >> 6;
    const int l  = threadIdx.x & 63;
    const int rw = l & 15;
    const int kb = (l >> 4) * 8;
    constexpr int STEPS = 32 / S;

    const float* ipA = img + (w * 16 + rw) * Dn + kq * (Dn / S) + kb;
    const int mrow = (rw < Mn) ? rw : 0;
    const float* ipB = mem + (size_t)c * (Mn * Dn) + mrow * Dn + kq * (Dn / S) + kb;

    f32x4 acc0 = {0.f, 0.f, 0.f, 0.f};
    f32x4 acc1 = {0.f, 0.f, 0.f, 0.f};
#pragma unroll
    for (int r = 0; r < STEPS / 2; ++r) {
        const int k0 = 64 * r;
        const float4 a00 = *reinterpret_cast<const float4*>(ipA + k0);
        const float4 a01 = *reinterpret_cast<const float4*>(ipA + k0 + 4);
        const float4 b00 = *reinterpret_cast<const float4*>(ipB + k0);
        const float4 b01 = *reinterpret_cast<const float4*>(ipB + k0 + 4);
        const float4 a10 = *reinterpret_cast<const float4*>(ipA + k0 + 32);
        const float4 a11 = *reinterpret_cast<const float4*>(ipA + k0 + 36);
        const float4 b10 = *reinterpret_cast<const float4*>(ipB + k0 + 32);
        const float4 b11 = *reinterpret_cast<const float4*>(ipB + k0 + 36);
        acc0 = __builtin_amdgcn_mfma_f32_16x16x32_bf16(
            pack_bf16x8(a00, a01), pack_bf16x8(b00, b01), acc0, 0, 0, 0);
        acc1 = __builtin_amdgcn_mfma_f32_16x16x32_bf16(
            pack_bf16x8(a10, a11), pack_bf16x8(b10, b11), acc1, 0, 0, 0);
    }
    const f32x4 acc = acc0 + acc1;

    const int mcol = l & 15;
    if (mcol < Mn) {
        const int br = w * 16 + (l >> 4) * 4;
        float* o = simp + ((size_t)kq * Cn + c) * (Bn * Mn) + br * Mn + mcol;
        o[0 * Mn] = acc[0];
        o[1 * Mn] = acc[1];
        o[2 * Mn] = acc[2];
        o[3 * Mn] = acc[3];
    }
}

template <int S>
__global__ __launch_bounds__(256) void gram_kernel_u(
    const float* __restrict__ mem, float* __restrict__ gramp) {
    const int c  = blockIdx.x * 4 + (threadIdx.x >> 6);
    const int kq = blockIdx.y;
    const int l  = threadIdx.x & 63;
    const int rw = l & 15;
    const int kb = (l >> 4) * 8;
    constexpr int STEPS = 32 / S;

    const int mrow = (rw < Mn) ? rw : 0;
    const float* ip = mem + (size_t)c * (Mn * Dn) + mrow * Dn + kq * (Dn / S) + kb;

    f32x4 acc0 = {0.f, 0.f, 0.f, 0.f};
    f32x4 acc1 = {0.f, 0.f, 0.f, 0.f};
#pragma unroll
    for (int r = 0; r < STEPS / 2; ++r) {
        const int k0 = 64 * r;
        const float4 a00 = *reinterpret_cast<const float4*>(ip + k0);
        const float4 a01 = *reinterpret_cast<const float4*>(ip + k0 + 4);
        const float4 a10 = *reinterpret_cast<const float4*>(ip + k0 + 32);
        const float4 a11 = *reinterpret_cast<const float4*>(ip + k0 + 36);
        const bf16x8 f0 = pack_bf16x8(a00, a01);
        const bf16x8 f1 = pack_bf16x8(a10, a11);
        acc0 = __builtin_amdgcn_mfma_f32_16x16x32_bf16(f0, f0, acc0, 0, 0, 0);
        acc1 = __builtin_amdgcn_mfma_f32_16x16x32_bf16(f1, f1, acc1, 0, 0, 0);
    }
    const f32x4 acc = acc0 + acc1;

    const int col = l & 15;
    const int r0  = (l >> 4) * 4;
    if (col < Mn) {
        float* o = gramp + ((size_t)kq * Cn + c) * (Mn * Mn) + col;
        if (r0 + 0 < Mn) o[(r0 + 0) * Mn] = acc[0];
        if (r0 + 1 < Mn) o[(r0 + 1) * Mn] = acc[1];
        if (r0 + 2 < Mn) o[(r0 + 2) * Mn] = acc[2];
        if (r0 + 3 < Mn) o[(r0 + 3) * Mn] = acc[3];
    }
}

template <int S>
__global__ __launch_bounds__(256) void finish_kernel_u(
    const float* __restrict__ simp, const float* __restrict__ gramp,
    float* __restrict__ out) {
    const int b = threadIdx.x & 63;
    const int c = blockIdx.x * 4 + (threadIdx.x >> 6);

    const float* sp = simp + (size_t)c * (Bn * Mn) + b * Mn;
    const float* gp = gramp + (size_t)c * (Mn * Mn);
    constexpr size_t SIMSTR  = (size_t)Cn * Bn * Mn;
    constexpr size_t GRAMSTR = (size_t)Cn * Mn * Mn;

    float w[Mn];
    float numer = 0.f;
#pragma unroll
    for (int m = 0; m < Mn; ++m) {
        float s = 0.f;
#pragma unroll
        for (int q = 0; q < S; ++q) s += sp[q * SIMSTR + m];
        w[m]  = __expf(BETA * (s - 1.f));
        numer = fmaf(w[m], s, numer);
    }
    float den2 = 0.f;
#pragma unroll
    for (int i = 0; i < Mn; ++i) {
        float row = 0.f;
#pragma unroll
        for (int j = 0; j < Mn; ++j) {
            float Gv = 0.f;
#pragma unroll
            for (int q = 0; q < S; ++q) Gv += gp[q * GRAMSTR + i * Mn + j];
            row = fmaf(w[j], Gv, row);
        }
        den2 = fmaf(w[i], row, den2);
    }
    out[b * Cn + c] = 100.f * numer / sqrtf(den2);
}

extern "C" void kernel_launch(void* const* d_in, const int* in_sizes, int n_in,
                              void* d_out, int out_size, void* d_ws, size_t ws_size,
                              hipStream_t stream) {
    const float* img = (const float*)d_in[0];  // [64][1024] f32
    const float* mem = (const float*)d_in[1];  // [1000][11][1024] f32
    float* out = (float*)d_out;                // [64][1000] f32
    (void)in_sizes; (void)n_in; (void)out_size;

    constexpr size_t IMGP_B  = (size_t)4 * 32 * 64 * 16;     // 128 KB
    constexpr size_t MEMP_B  = (size_t)Cn * 32 * 64 * 16;    // 32.8 MB
    constexpr size_t GRAM2_B = (size_t)Cn * Mn * Mn * 4;     // 484 KB
    constexpr size_t SIMP_B  = (size_t)Cn * Bn * Mn * 4;     // per slice

    char* base = (char*)d_ws;
    const size_t need_fused = IMGP_B + MEMP_B + GRAM2_B;              // ~33.4 MB
    const size_t need_u4    = 4 * SIMP_B + 4 * GRAM2_B;               // ~13.2 MB

    if (ws_size >= need_fused) {
        bf16x8* imgP  = (bf16x8*)base;
        bf16x8* memP  = (bf16x8*)(base + IMGP_B);
        float*  gram2 = (float*)(base + IMGP_B + MEMP_B);
        pack_img_kernel<<<dim3(32), dim3(256), 0, stream>>>(img, imgP);
        packgram_kernel<<<dim3(Cn), dim3(256), 0, stream>>>(mem, memP, gram2);
        simfin_kernel<<<dim3(Cn), dim3(256), 0, stream>>>(imgP, memP, gram2, out);
    } else if (ws_size >= need_u4) {
        constexpr int S = 4;
        float* simp  = (float*)base;
        float* gramp = simp + (size_t)S * Cn * Bn * Mn;
        sim_kernel_u<S><<<dim3(Cn, S), dim3(256), 0, stream>>>(img, mem, simp);
        gram_kernel_u<S><<<dim3(Cn / 4, S), dim3(256), 0, stream>>>(mem, gramp);
        finish_kernel_u<S><<<dim3(Cn / 4), dim3(256), 0, stream>>>(simp, gramp, out);
    } else {
        constexpr int S = 1;
        float* simp  = (float*)base;
        float* gramp = simp + (size_t)S * Cn * Bn * Mn;
        sim_kernel_u<S><<<dim3(Cn, S), dim3(256), 0, stream>>>(img, mem, simp);
        gram_kernel_u<S><<<dim3(Cn / 4, S), dim3(256), 0, stream>>>(mem, gramp);
        finish_kernel_u<S><<<dim3(Cn / 4), dim3(256), 0, stream>>>(simp, gramp, out);
    }
}